// Round 1
// baseline (430.437 us; speedup 1.0000x reference)
//
#include <hip/hip_runtime.h>

#define NB 4096
#define MM 64
#define DD 256
#define LN_EPS 1e-5f

__global__ __launch_bounds__(256)
void asc_fused(const float* __restrict__ head_left,
               const float* __restrict__ rel_left,
               const float* __restrict__ tail_left,
               const float* __restrict__ head_right,
               const float* __restrict__ rel_right,
               const float* __restrict__ tail_right,
               const unsigned char* __restrict__ mask_left,
               const unsigned char* __restrict__ mask_right,
               const float* __restrict__ bw,
               const float* __restrict__ wt,
               const float* __restrict__ wh,
               const float* __restrict__ gamma,
               const float* __restrict__ beta,
               float* __restrict__ out)
{
    const int b    = blockIdx.x;
    const int t    = threadIdx.x;
    const int lane = t & 63;
    const int w    = t >> 6;

    __shared__ float hs_s[2][DD];     // head_left, head_right
    __shared__ float weak_s[DD];
    __shared__ float hW_s[DD];
    __shared__ float x_s[DD];
    __shared__ float part_s[4 * DD];
    __shared__ float att_s[MM];
    __shared__ float red1_s[4];
    __shared__ float red2_s[4];

    const float hl = head_left[b * DD + t];
    const float hr = head_right[b * DD + t];
    hs_s[0][t] = hl;
    hs_s[1][t] = hr;
    weak_s[t]  = hr - hl;
    const float g  = gamma[t];
    const float be = beta[t];

    // ---- mask dtype detection (bool-as-u8 vs int32), identical in all blocks ----
    // If masks are int32 with values 0/1, every byte at offset i%4!=0 is zero.
    // If masks are 1-byte bools (random 0/1), some of those bytes are nonzero
    // with probability 1 - 2^-48.
    bool mask_u8;
    {
        unsigned char v = mask_left[lane];
        unsigned long long bal = __ballot(((lane & 3) != 0) && (v != 0));
        mask_u8 = (bal != 0ULL);
    }
    __syncthreads();

    // ---- bilinear: hW[d] = sum_k weak[k] * bw[k*DD + d] ----
    // wave w owns k in [w*64, w*64+64); lanes cover the 256-wide output row as float4.
    {
        float4 acc = make_float4(0.f, 0.f, 0.f, 0.f);
        for (int i = 0; i < 64; ++i) {
            const int k = w * 64 + i;
            const float wk = weak_s[k];
            const float4 v = *(const float4*)(bw + k * DD + 4 * lane);
            acc.x += wk * v.x; acc.y += wk * v.y; acc.z += wk * v.z; acc.w += wk * v.w;
        }
        *(float4*)(part_s + w * DD + 4 * lane) = acc;
    }
    __syncthreads();
    hW_s[t] = part_s[t] + part_s[DD + t] + part_s[2 * DD + t] + part_s[3 * DD + t];
    __syncthreads();

    for (int side = 0; side < 2; ++side) {
        const float* __restrict__ rel  = side ? rel_right  : rel_left;
        const float* __restrict__ tail = side ? tail_right : tail_left;
        const unsigned char* __restrict__ mask = side ? mask_right : mask_left;

        // ---- scores: score[m] = dot(hW, rel[b,m,:]) ; wave w handles m = w*16..w*16+15
        {
            const float4 hw4 = *(const float4*)(hW_s + 4 * lane);
            for (int i = 0; i < 16; ++i) {
                const int m = w * 16 + i;
                const float4 r4 = *(const float4*)(rel + (size_t)(b * MM + m) * DD + 4 * lane);
                float p = hw4.x * r4.x + hw4.y * r4.y + hw4.z * r4.z + hw4.w * r4.w;
                #pragma unroll
                for (int off = 32; off >= 1; off >>= 1) p += __shfl_xor(p, off);
                if (lane == 0) att_s[m] = p;
            }
        }
        __syncthreads();

        // ---- masked softmax over m (wave 0) ----
        if (w == 0) {
            float s = att_s[lane];
            const bool msk = mask_u8
                ? (mask[b * MM + lane] != 0)
                : (((const int*)(const void*)mask)[b * MM + lane] != 0);
            if (msk) s = -__builtin_inff();
            float mx = s;
            #pragma unroll
            for (int off = 32; off >= 1; off >>= 1) mx = fmaxf(mx, __shfl_xor(mx, off));
            const float e = __expf(s - mx);
            float sum = e;
            #pragma unroll
            for (int off = 32; off >= 1; off >>= 1) sum += __shfl_xor(sum, off);
            att_s[lane] = e / sum;
        }
        __syncthreads();

        // ---- ctx[d] = sum_m att[m] * tail[b,m,d] ----
        {
            float4 acc = make_float4(0.f, 0.f, 0.f, 0.f);
            for (int i = 0; i < 16; ++i) {
                const int m = w * 16 + i;
                const float a = att_s[m];
                const float4 v = *(const float4*)(tail + (size_t)(b * MM + m) * DD + 4 * lane);
                acc.x += a * v.x; acc.y += a * v.y; acc.z += a * v.z; acc.w += a * v.w;
            }
            *(float4*)(part_s + w * DD + 4 * lane) = acc;
        }
        __syncthreads();
        x_s[t] = part_s[t] + part_s[DD + t] + part_s[2 * DD + t] + part_s[3 * DD + t];
        __syncthreads();

        // ---- out[d] = dot(ctx, wt[d,:]) + dot(head_side, wh[d,:]) ; row-dot, coalesced
        float o = 0.f;
        {
            const float4 x4 = *(const float4*)(x_s + 4 * lane);
            const float4 h4 = *(const float4*)(&hs_s[side][0] + 4 * lane);
            for (int j = 0; j < 64; ++j) {
                const int d = w * 64 + j;
                const float4 a4 = *(const float4*)(wt + d * DD + 4 * lane);
                const float4 b4 = *(const float4*)(wh + d * DD + 4 * lane);
                float p = x4.x * a4.x + x4.y * a4.y + x4.z * a4.z + x4.w * a4.w
                        + h4.x * b4.x + h4.y * b4.y + h4.z * b4.z + h4.w * b4.w;
                #pragma unroll
                for (int off = 32; off >= 1; off >>= 1) p += __shfl_xor(p, off);
                if (lane == j) o = p;   // thread t owns d = w*64 + lane = t
            }
        }

        const float hval = side ? hr : hl;
        const float y = fmaxf(o, 0.f) + hval;   // relu + residual

        // ---- LayerNorm over d=256 (block-wide) ----
        float s1 = y, s2 = y * y;
        #pragma unroll
        for (int off = 32; off >= 1; off >>= 1) {
            s1 += __shfl_xor(s1, off);
            s2 += __shfl_xor(s2, off);
        }
        if (lane == 0) { red1_s[w] = s1; red2_s[w] = s2; }
        __syncthreads();
        const float tot1 = red1_s[0] + red1_s[1] + red1_s[2] + red1_s[3];
        const float tot2 = red2_s[0] + red2_s[1] + red2_s[2] + red2_s[3];
        const float mu   = tot1 * (1.0f / DD);
        const float var  = tot2 * (1.0f / DD) - mu * mu;
        const float rstd = rsqrtf(var + LN_EPS);
        out[(size_t)side * NB * DD + (size_t)b * DD + t] = (y - mu) * rstd * g + be;
        __syncthreads();   // protect att_s/part_s/red*_s reuse next side
    }
}

extern "C" void kernel_launch(void* const* d_in, const int* in_sizes, int n_in,
                              void* d_out, int out_size, void* d_ws, size_t ws_size,
                              hipStream_t stream) {
    const float* head_left  = (const float*)d_in[0];
    const float* rel_left   = (const float*)d_in[1];
    const float* tail_left  = (const float*)d_in[2];
    const float* head_right = (const float*)d_in[3];
    const float* rel_right  = (const float*)d_in[4];
    const float* tail_right = (const float*)d_in[5];
    const unsigned char* mask_left  = (const unsigned char*)d_in[6];
    const unsigned char* mask_right = (const unsigned char*)d_in[7];
    const float* bw    = (const float*)d_in[8];
    const float* wt    = (const float*)d_in[9];
    const float* wh    = (const float*)d_in[10];
    const float* gamma = (const float*)d_in[11];
    const float* beta  = (const float*)d_in[12];
    float* out = (float*)d_out;

    asc_fused<<<dim3(NB), dim3(256), 0, stream>>>(
        head_left, rel_left, tail_left, head_right, rel_right, tail_right,
        mask_left, mask_right, bw, wt, wh, gamma, beta, out);
}

// Round 2
// 315.423 us; speedup vs baseline: 1.3646x; 1.3646x over previous
//
#include <hip/hip_runtime.h>

#define NB 4096
#define MM 64
#define DD 256
#define LN_EPS 1e-5f

// ws layout (floats):
//   [0,            512*DD)   wcat : [wt^T ; wh^T]  (512 rows x 256)
//   [WS_HW,  +NB*DD)          hW
//   [WS_CTX, +2*NB*DD)        ctx  (row = side*NB + b)
#define WS_WCAT 0
#define WS_HW   (512 * DD)
#define WS_CTX  (WS_HW + NB * DD)

// ---------------- T: transpose wt, wh into wcat ----------------
__global__ __launch_bounds__(256)
void k_transpose(const float* __restrict__ wt, const float* __restrict__ wh,
                 float* __restrict__ wcat)
{
    // 32 blocks: mat = bid>>4, tile = bid&15 -> (dBase, kBase) 64x64 tiles
    const int mat   = blockIdx.x >> 4;
    const int tile  = blockIdx.x & 15;
    const int dBase = (tile >> 2) * 64;
    const int kBase = (tile & 3) * 64;
    const float* __restrict__ w = mat ? wh : wt;

    __shared__ float tile_s[64][65];
    const int c  = threadIdx.x & 63;
    const int rr = threadIdx.x >> 6;

    #pragma unroll
    for (int r = rr; r < 64; r += 4)
        tile_s[r][c] = w[(dBase + r) * DD + kBase + c];   // coalesced read over k
    __syncthreads();
    #pragma unroll
    for (int kr = rr; kr < 64; kr += 4)
        wcat[(mat * 256 + kBase + kr) * DD + dBase + c] = tile_s[c][kr]; // coalesced write over d
}

// ---------------- A: hW[b,:] = (head_right-head_left)[b,:] @ bw ----------------
__global__ __launch_bounds__(256)
void k_bilinear(const float* __restrict__ head_left,
                const float* __restrict__ head_right,
                const float* __restrict__ bw,
                float* __restrict__ hW)
{
    const int blk  = blockIdx.x;          // 256 blocks x 16 rows
    const int t    = threadIdx.x;
    const int lane = t & 63;
    const int w    = t >> 6;

    __shared__ float weak_s[16][DD];
    #pragma unroll
    for (int r = 0; r < 16; ++r) {
        const size_t idx = (size_t)(blk * 16 + r) * DD + t;
        weak_s[r][t] = head_right[idx] - head_left[idx];
    }
    __syncthreads();

    float4 acc[4];
    #pragma unroll
    for (int r = 0; r < 4; ++r) acc[r] = make_float4(0.f, 0.f, 0.f, 0.f);

    for (int k = 0; k < DD; ++k) {
        const float4 w4 = *(const float4*)(bw + k * DD + 4 * lane);
        #pragma unroll
        for (int r = 0; r < 4; ++r) {
            const float x = weak_s[4 * w + r][k];
            acc[r].x += x * w4.x; acc[r].y += x * w4.y;
            acc[r].z += x * w4.z; acc[r].w += x * w4.w;
        }
    }
    #pragma unroll
    for (int r = 0; r < 4; ++r)
        *(float4*)(hW + (size_t)(blk * 16 + 4 * w + r) * DD + 4 * lane) = acc[r];
}

// ---------------- attn: per (b,side): scores -> masked softmax -> ctx ----------------
__global__ __launch_bounds__(256)
void k_attn(const float* __restrict__ rel_left,
            const float* __restrict__ tail_left,
            const float* __restrict__ rel_right,
            const float* __restrict__ tail_right,
            const unsigned char* __restrict__ mask_left,
            const unsigned char* __restrict__ mask_right,
            const float* __restrict__ hW,
            float* __restrict__ ctx)
{
    const int b    = blockIdx.x >> 1;
    const int side = blockIdx.x & 1;
    const int t    = threadIdx.x;
    const int lane = t & 63;
    const int w    = t >> 6;

    const float* __restrict__ rel  = side ? rel_right  : rel_left;
    const float* __restrict__ tail = side ? tail_right : tail_left;
    const unsigned char* __restrict__ mask = side ? mask_right : mask_left;

    __shared__ float att_s[MM];
    __shared__ float part_s[4][DD];

    const float4 hw4 = *(const float4*)(hW + (size_t)b * DD + 4 * lane);

    // scores: wave w owns m = w*16 .. w*16+15, coalesced 1KB row loads
    #pragma unroll 4
    for (int i = 0; i < 16; ++i) {
        const int m = w * 16 + i;
        const float4 r4 = *(const float4*)(rel + ((size_t)(b * MM + m)) * DD + 4 * lane);
        float p = hw4.x * r4.x + hw4.y * r4.y + hw4.z * r4.z + hw4.w * r4.w;
        #pragma unroll
        for (int off = 32; off >= 1; off >>= 1) p += __shfl_xor(p, off);
        if (lane == 0) att_s[m] = p;
    }
    __syncthreads();

    // masked softmax on wave 0
    if (w == 0) {
        // mask dtype detection: int32 0/1 -> bytes at i%4!=0 all zero
        unsigned char v = mask_left[lane];
        const bool mask_u8 = (__ballot(((lane & 3) != 0) && (v != 0)) != 0ULL);

        float s = att_s[lane];
        const bool msk = mask_u8
            ? (mask[b * MM + lane] != 0)
            : (((const int*)(const void*)mask)[b * MM + lane] != 0);
        if (msk) s = -__builtin_inff();
        float mx = s;
        #pragma unroll
        for (int off = 32; off >= 1; off >>= 1) mx = fmaxf(mx, __shfl_xor(mx, off));
        const float e = __expf(s - mx);
        float sum = e;
        #pragma unroll
        for (int off = 32; off >= 1; off >>= 1) sum += __shfl_xor(sum, off);
        att_s[lane] = e / sum;
    }
    __syncthreads();

    // ctx partial per wave
    float4 acc = make_float4(0.f, 0.f, 0.f, 0.f);
    #pragma unroll 4
    for (int i = 0; i < 16; ++i) {
        const int m = w * 16 + i;
        const float a = att_s[m];
        const float4 v = *(const float4*)(tail + ((size_t)(b * MM + m)) * DD + 4 * lane);
        acc.x += a * v.x; acc.y += a * v.y; acc.z += a * v.z; acc.w += a * v.w;
    }
    *(float4*)(&part_s[w][4 * lane]) = acc;
    __syncthreads();

    const float sum = part_s[0][t] + part_s[1][t] + part_s[2][t] + part_s[3][t];
    ctx[(size_t)(side * NB + b) * DD + t] = sum;
}

// ---------------- E: out = LN(relu([ctx|head] @ wcat^T-ish) + head) ----------------
// out[r][d] = relu( sum_{k<256} ctx[r][k]*wcat[k][d] + sum_{k} head[r][k]*wcat[256+k][d] ) + head[r][d] -> LN
__global__ __launch_bounds__(256)
void k_outln(const float* __restrict__ ctx,
             const float* __restrict__ head_left,
             const float* __restrict__ head_right,
             const float* __restrict__ wcat,
             const float* __restrict__ gamma,
             const float* __restrict__ beta,
             float* __restrict__ out)
{
    const int blk  = blockIdx.x;           // 256 blocks x 32 rows
    const int t    = threadIdx.x;
    const int lane = t & 63;
    const int w    = t >> 6;

    __shared__ float x_s[32][512];          // [r][0:256)=ctx, [256:512)=head_side

    const int  side = (blk * 32) >> 12;     // uniform per block (4096 % 32 == 0)
    const float* __restrict__ head = side ? head_right : head_left;

    // cooperative load: 32*512 floats, 256 threads -> 64 each, coalesced
    for (int i = 0; i < 64; ++i) {
        const int idx = i * 256 + t;
        const int r   = idx >> 9;
        const int c   = idx & 511;
        const int rg  = blk * 32 + r;       // global row = side*NB + b
        const int bb  = rg & (NB - 1);
        x_s[r][c] = (c < DD) ? ctx[(size_t)rg * DD + c]
                             : head[(size_t)bb * DD + (c - DD)];
    }
    __syncthreads();

    float4 acc[8];
    #pragma unroll
    for (int r = 0; r < 8; ++r) acc[r] = make_float4(0.f, 0.f, 0.f, 0.f);

    for (int k = 0; k < 512; ++k) {
        const float4 w4 = *(const float4*)(wcat + (size_t)k * DD + 4 * lane);
        #pragma unroll
        for (int r = 0; r < 8; ++r) {
            const float x = x_s[8 * w + r][k];
            acc[r].x += x * w4.x; acc[r].y += x * w4.y;
            acc[r].z += x * w4.z; acc[r].w += x * w4.w;
        }
    }

    const float4 g4 = *(const float4*)(gamma + 4 * lane);
    const float4 b4 = *(const float4*)(beta  + 4 * lane);

    #pragma unroll
    for (int r = 0; r < 8; ++r) {
        const int rl = 8 * w + r;
        const float4 h4 = *(const float4*)(&x_s[rl][DD + 4 * lane]);
        float4 y;
        y.x = fmaxf(acc[r].x, 0.f) + h4.x;
        y.y = fmaxf(acc[r].y, 0.f) + h4.y;
        y.z = fmaxf(acc[r].z, 0.f) + h4.z;
        y.w = fmaxf(acc[r].w, 0.f) + h4.w;

        float s1 = y.x + y.y + y.z + y.w;
        float s2 = y.x * y.x + y.y * y.y + y.z * y.z + y.w * y.w;
        #pragma unroll
        for (int off = 32; off >= 1; off >>= 1) {
            s1 += __shfl_xor(s1, off);
            s2 += __shfl_xor(s2, off);
        }
        const float mu   = s1 * (1.0f / DD);
        const float var  = s2 * (1.0f / DD) - mu * mu;
        const float rstd = rsqrtf(var + LN_EPS);

        float4 o;
        o.x = (y.x - mu) * rstd * g4.x + b4.x;
        o.y = (y.y - mu) * rstd * g4.y + b4.y;
        o.z = (y.z - mu) * rstd * g4.z + b4.z;
        o.w = (y.w - mu) * rstd * g4.w + b4.w;
        *(float4*)(out + (size_t)(blk * 32 + rl) * DD + 4 * lane) = o;
    }
}

extern "C" void kernel_launch(void* const* d_in, const int* in_sizes, int n_in,
                              void* d_out, int out_size, void* d_ws, size_t ws_size,
                              hipStream_t stream) {
    const float* head_left  = (const float*)d_in[0];
    const float* rel_left   = (const float*)d_in[1];
    const float* tail_left  = (const float*)d_in[2];
    const float* head_right = (const float*)d_in[3];
    const float* rel_right  = (const float*)d_in[4];
    const float* tail_right = (const float*)d_in[5];
    const unsigned char* mask_left  = (const unsigned char*)d_in[6];
    const unsigned char* mask_right = (const unsigned char*)d_in[7];
    const float* bw    = (const float*)d_in[8];
    const float* wt    = (const float*)d_in[9];
    const float* wh    = (const float*)d_in[10];
    const float* gamma = (const float*)d_in[11];
    const float* beta  = (const float*)d_in[12];
    float* out = (float*)d_out;

    float* ws   = (float*)d_ws;
    float* wcat = ws + WS_WCAT;
    float* hW   = ws + WS_HW;
    float* ctx  = ws + WS_CTX;

    k_transpose<<<dim3(32),   dim3(256), 0, stream>>>(wt, wh, wcat);
    k_bilinear <<<dim3(256),  dim3(256), 0, stream>>>(head_left, head_right, bw, hW);
    k_attn     <<<dim3(8192), dim3(256), 0, stream>>>(rel_left, tail_left, rel_right, tail_right,
                                                      mask_left, mask_right, hW, ctx);
    k_outln    <<<dim3(256),  dim3(256), 0, stream>>>(ctx, head_left, head_right, wcat,
                                                      gamma, beta, out);
}